// Round 1
// baseline (1409.003 us; speedup 1.0000x reference)
//
#include <hip/hip_runtime.h>
#include <hip/hip_fp16.h>

typedef _Float16 f16x8 __attribute__((ext_vector_type(8)));
typedef _Float16 f16x4 __attribute__((ext_vector_type(4)));
typedef float f32x4 __attribute__((ext_vector_type(4)));

static constexpr int M_ROWS = 32768;   // B*N
static constexpr int N_CB   = 8192;    // K codebook entries
static constexpr int CDIM   = 512;     // C
static constexpr int BM = 128, BN = 128, BKC = 32;
static constexpr int NBLK = N_CB / BN; // 64 column blocks
static constexpr float TAU = 0.02f;    // near-tie band; >> approx error (~1e-4)

// ---- workspace layout (bytes) ----
static constexpr size_t AH_OFF   = 0;
static constexpr size_t AL_OFF   = AH_OFF + (size_t)M_ROWS * CDIM * 2;
static constexpr size_t BH_OFF   = AL_OFF + (size_t)M_ROWS * CDIM * 2;
static constexpr size_t BL_OFF   = BH_OFF + (size_t)N_CB * CDIM * 2;
static constexpr size_t CBSQ_OFF = BL_OFF + (size_t)N_CB * CDIM * 2;
static constexpr size_t PVAL_OFF = CBSQ_OFF + (size_t)N_CB * 4;
static constexpr size_t PPACK_OFF= PVAL_OFF + (size_t)M_ROWS * NBLK * 4;
static constexpr size_t FIDX_OFF = PPACK_OFF + (size_t)M_ROWS * NBLK * 4;
static constexpr size_t FCNT_OFF = FIDX_OFF + (size_t)M_ROWS * 4;
static constexpr size_t FROWS_OFF= FCNT_OFF + 64;
// total ~96.3 MB

__device__ __forceinline__ void gload_lds16(const void* g, void* l) {
    __builtin_amdgcn_global_load_lds(
        (const __attribute__((address_space(1))) void*)g,
        (__attribute__((address_space(3))) void*)l, 16, 0, 0);
}

// fp32 -> (fp16 hi, fp16 lo) split, vectorized float4
__global__ void vq_split(const float4* __restrict__ in, _Float16* __restrict__ hi,
                         _Float16* __restrict__ lo, int n4) {
    int i = blockIdx.x * 256 + threadIdx.x;
    const int stride = gridDim.x * 256;
    for (; i < n4; i += stride) {
        float4 v = in[i];
        f16x4 h, l;
        h[0] = (_Float16)v.x; l[0] = (_Float16)(v.x - (float)h[0]);
        h[1] = (_Float16)v.y; l[1] = (_Float16)(v.y - (float)h[1]);
        h[2] = (_Float16)v.z; l[2] = (_Float16)(v.z - (float)h[2]);
        h[3] = (_Float16)v.w; l[3] = (_Float16)(v.w - (float)h[3]);
        *(f16x4*)(hi + (size_t)i * 4) = h;
        *(f16x4*)(lo + (size_t)i * 4) = l;
    }
}

// ||c_k||^2, one wave per codebook row (tree-sum: low rounding error)
__global__ void vq_cbsq(const float* __restrict__ cb, float* __restrict__ cbsq) {
    const int gw = (blockIdx.x * 256 + threadIdx.x) >> 6;
    const int lane = threadIdx.x & 63;
    if (gw >= N_CB) return;
    const float4* r = (const float4*)(cb + (size_t)gw * CDIM);
    float4 a = r[lane * 2], b = r[lane * 2 + 1];
    float s = a.x*a.x + a.y*a.y + a.z*a.z + a.w*a.w
            + b.x*b.x + b.y*b.y + b.z*b.z + b.w*b.w;
#pragma unroll
    for (int m = 1; m < 64; m <<= 1) s += __shfl_xor(s, m, 64);
    if (lane == 0) cbsq[gw] = s;
}

// Main pass: scores[m,n] = 2*dot(x_m, c_n) + cbsq[n] via fp16x2 3-MFMA GEMM,
// per-row min/idx/count(<= min+TAU) over each 128-col tile.
__launch_bounds__(256)
__global__ void vq_gemm(const _Float16* __restrict__ Ah, const _Float16* __restrict__ Al,
                        const _Float16* __restrict__ Bh, const _Float16* __restrict__ Bl,
                        const float* __restrict__ cbsq,
                        float* __restrict__ pVal, int* __restrict__ pPack) {
    __shared__ _Float16 As_h[BM][BKC];
    __shared__ _Float16 As_l[BM][BKC];
    __shared__ _Float16 Bs_h[BN][BKC];
    __shared__ _Float16 Bs_l[BN][BKC];
    __shared__ float mV[BM][2];
    __shared__ int   mI[BM][2];
    __shared__ int   mC[BM][2];

    const int tid = threadIdx.x;
    const int wave = tid >> 6, lane = tid & 63;
    const int mblk = blockIdx.y, nblk = blockIdx.x;
    const int wm = (wave >> 1) * 64, wn = (wave & 1) * 64;

    f32x4 acc[4][4] = {};

    for (int s = 0; s < CDIM / BKC; ++s) {
        __syncthreads();
        {
            const size_t gco = (size_t)(s * BKC) + (lane & 3) * 8; // halves
#pragma unroll
            for (int it = 0; it < 2; ++it) {
                const int rl = wave * 16 + it * 64 + (lane >> 2);
                const int lofs = (wave * 16 + it * 64) * BKC; // halves, wave-uniform
                gload_lds16(Ah + (size_t)(mblk * BM + rl) * CDIM + gco, &As_h[0][0] + lofs);
                gload_lds16(Al + (size_t)(mblk * BM + rl) * CDIM + gco, &As_l[0][0] + lofs);
                gload_lds16(Bh + (size_t)(nblk * BN + rl) * CDIM + gco, &Bs_h[0][0] + lofs);
                gload_lds16(Bl + (size_t)(nblk * BN + rl) * CDIM + gco, &Bs_l[0][0] + lofs);
            }
        }
        asm volatile("s_waitcnt vmcnt(0)" ::: "memory");
        __syncthreads();

        const int k0 = (lane >> 4) * 8;
        const int ar = wm + (lane & 15);
        f16x8 ah[4], al4[4];
#pragma unroll
        for (int mi = 0; mi < 4; ++mi) {
            ah[mi]  = *(const f16x8*)&As_h[ar + mi * 16][k0];
            al4[mi] = *(const f16x8*)&As_l[ar + mi * 16][k0];
        }
#pragma unroll
        for (int ni = 0; ni < 4; ++ni) {
            const int br = wn + ni * 16 + (lane & 15);
            f16x8 bh = *(const f16x8*)&Bs_h[br][k0];
            f16x8 bl = *(const f16x8*)&Bs_l[br][k0];
#pragma unroll
            for (int mi = 0; mi < 4; ++mi) {
                acc[mi][ni] = __builtin_amdgcn_mfma_f32_16x16x32_f16(ah[mi],  bh, acc[mi][ni], 0, 0, 0);
                acc[mi][ni] = __builtin_amdgcn_mfma_f32_16x16x32_f16(ah[mi],  bl, acc[mi][ni], 0, 0, 0);
                acc[mi][ni] = __builtin_amdgcn_mfma_f32_16x16x32_f16(al4[mi], bh, acc[mi][ni], 0, 0, 0);
            }
        }
    }
    __syncthreads();

    // ---- epilogue: per-row (min, idx, count within TAU) over this 128-col tile ----
    float cb4[4]; int col4[4];
#pragma unroll
    for (int ni = 0; ni < 4; ++ni) {
        const int c = nblk * BN + wn + ni * 16 + (lane & 15);
        col4[ni] = c; cb4[ni] = cbsq[c];
    }
#pragma unroll
    for (int mi = 0; mi < 4; ++mi) {
#pragma unroll
        for (int j = 0; j < 4; ++j) {
            float sv[4];
#pragma unroll
            for (int ni = 0; ni < 4; ++ni) sv[ni] = 2.0f * acc[mi][ni][j] + cb4[ni];
            float bv = sv[0]; int bi = col4[0];
#pragma unroll
            for (int ni = 1; ni < 4; ++ni)
                if (sv[ni] < bv) { bv = sv[ni]; bi = col4[ni]; } // cols increase with ni: tie keeps lower
#pragma unroll
            for (int m = 1; m < 16; m <<= 1) {
                float ov = __shfl_xor(bv, m, 64);
                int   oi = __shfl_xor(bi, m, 64);
                if (ov < bv || (ov == bv && oi < bi)) { bv = ov; bi = oi; }
            }
            int cnt = 0;
#pragma unroll
            for (int ni = 0; ni < 4; ++ni) cnt += (sv[ni] <= bv + TAU) ? 1 : 0;
#pragma unroll
            for (int m = 1; m < 16; m <<= 1) cnt += __shfl_xor(cnt, m, 64);
            if ((lane & 15) == 0) {
                const int r = wm + mi * 16 + (lane >> 4) * 4 + j;
                const int h = wn >> 6;
                mV[r][h] = bv; mI[r][h] = bi; mC[r][h] = cnt;
            }
        }
    }
    __syncthreads();
    if (tid < BM) {
        const float v0 = mV[tid][0], v1 = mV[tid][1];
        const int i0 = mI[tid][0], i1 = mI[tid][1];
        const int c0 = mC[tid][0], c1 = mC[tid][1];
        float bv; int bi;
        if (v1 < v0) { bv = v1; bi = i1; } else { bv = v0; bi = i0; } // tie -> lower idx (i0)
        int cnt = ((v0 <= bv + TAU) ? c0 : 0) + ((v1 <= bv + TAU) ? c1 : 0);
        if (cnt > 7) cnt = 7;
        const size_t o = (size_t)nblk * M_ROWS + (size_t)mblk * BM + tid; // transposed: coalesced store
        pVal[o] = bv;
        pPack[o] = (bi << 3) | cnt;
    }
}

// Merge 64 column-block partials per row; flag rows with >=2 candidates within TAU of global min.
__global__ void vq_reduce(const float* __restrict__ pVal, const int* __restrict__ pPack,
                          int* __restrict__ finalIdx, int* __restrict__ flagCnt,
                          int* __restrict__ flagRows) {
    const int row = blockIdx.x * 4 + (threadIdx.x >> 6);
    const int lane = threadIdx.x & 63;
    const size_t o = (size_t)lane * M_ROWS + row;
    const float v = pVal[o];
    const int pk = pPack[o];
    const int idx = pk >> 3, cnt = pk & 7;
    float bv = v; int bi = idx;
#pragma unroll
    for (int m = 1; m < 64; m <<= 1) {
        float ov = __shfl_xor(bv, m, 64);
        int   oi = __shfl_xor(bi, m, 64);
        if (ov < bv || (ov == bv && oi < bi)) { bv = ov; bi = oi; }
    }
    int r = (v <= bv + TAU) ? cnt : 0;
#pragma unroll
    for (int m = 1; m < 64; m <<= 1) r += __shfl_xor(r, m, 64);
    if (lane == 0) {
        finalIdx[row] = bi;
        if (r >= 2) { int p = atomicAdd(flagCnt, 1); flagRows[p] = row; }
    }
}

// Exact fp64 rescore of flagged rows (score = sum c*(c+2x); in_sq const -> dropped).
// One wave per candidate: coalesced float4 reads, butterfly-sum.
__launch_bounds__(1024)
__global__ void vq_rescue(const float* __restrict__ z, const float* __restrict__ cb,
                          const int* __restrict__ flagCnt, const int* __restrict__ flagRows,
                          int* __restrict__ finalIdx) {
    __shared__ float xs[CDIM];
    __shared__ double sV[16];
    __shared__ int sI[16];
    const int tid = threadIdx.x;
    const int wv = tid >> 6, lane = tid & 63;
    const int nf = *flagCnt;
    for (int f = blockIdx.x; f < nf; f += gridDim.x) {
        const int row = flagRows[f];
        __syncthreads();
        if (tid < CDIM) xs[tid] = z[(size_t)row * CDIM + tid];
        __syncthreads();
        const float4 x0 = ((const float4*)xs)[lane * 2];
        const float4 x1 = ((const float4*)xs)[lane * 2 + 1];
        double bv = 1e300; int bi = 0;
        for (int k = wv; k < N_CB; k += 16) {
            const float4* cr = (const float4*)(cb + (size_t)k * CDIM) + lane * 2;
            const float4 c0 = cr[0], c1 = cr[1];
            double s = 0.0;
            s += (double)c0.x * ((double)c0.x + 2.0 * (double)x0.x);
            s += (double)c0.y * ((double)c0.y + 2.0 * (double)x0.y);
            s += (double)c0.z * ((double)c0.z + 2.0 * (double)x0.z);
            s += (double)c0.w * ((double)c0.w + 2.0 * (double)x0.w);
            s += (double)c1.x * ((double)c1.x + 2.0 * (double)x1.x);
            s += (double)c1.y * ((double)c1.y + 2.0 * (double)x1.y);
            s += (double)c1.z * ((double)c1.z + 2.0 * (double)x1.z);
            s += (double)c1.w * ((double)c1.w + 2.0 * (double)x1.w);
#pragma unroll
            for (int m = 1; m < 64; m <<= 1) s += __shfl_xor(s, m, 64);
            if (s < bv) { bv = s; bi = k; }
        }
        if (lane == 0) { sV[wv] = bv; sI[wv] = bi; }
        __syncthreads();
        if (tid == 0) {
            double b = sV[0]; int i = sI[0];
            for (int w = 1; w < 16; ++w)
                if (sV[w] < b || (sV[w] == b && sI[w] < i)) { b = sV[w]; i = sI[w]; }
            finalIdx[row] = i;
        }
    }
}

// Gather codes into both outputs + idx as float.
__global__ void vq_gather(const float4* __restrict__ cb4, const int* __restrict__ finalIdx,
                          float4* __restrict__ out0, float4* __restrict__ out1,
                          float* __restrict__ out2) {
    const int tid = threadIdx.x;
    const int row = blockIdx.x * 2 + (tid >> 7);
    const int c4 = tid & 127;
    const int id = finalIdx[row];
    const float4 v = cb4[(size_t)id * 128 + c4];
    const size_t o = (size_t)row * 128 + c4;
    out0[o] = v;
    out1[o] = v;
    if (c4 == 0) out2[row] = (float)id;
}

extern "C" void kernel_launch(void* const* d_in, const int* in_sizes, int n_in,
                              void* d_out, int out_size, void* d_ws, size_t ws_size,
                              hipStream_t stream) {
    const float* z  = (const float*)d_in[0];
    const float* cb = (const float*)d_in[1];
    char* ws = (char*)d_ws;
    _Float16* Ah = (_Float16*)(ws + AH_OFF);
    _Float16* Al = (_Float16*)(ws + AL_OFF);
    _Float16* Bh = (_Float16*)(ws + BH_OFF);
    _Float16* Bl = (_Float16*)(ws + BL_OFF);
    float* cbsq  = (float*)(ws + CBSQ_OFF);
    float* pVal  = (float*)(ws + PVAL_OFF);
    int* pPack   = (int*)(ws + PPACK_OFF);
    int* fIdx    = (int*)(ws + FIDX_OFF);
    int* fCnt    = (int*)(ws + FCNT_OFF);
    int* fRows   = (int*)(ws + FROWS_OFF);

    hipMemsetAsync(fCnt, 0, 4, stream);
    vq_split<<<2048, 256, 0, stream>>>((const float4*)z, Ah, Al, M_ROWS * CDIM / 4);
    vq_split<<<1024, 256, 0, stream>>>((const float4*)cb, Bh, Bl, N_CB * CDIM / 4);
    vq_cbsq<<<N_CB / 4, 256, 0, stream>>>(cb, cbsq);
    dim3 g(N_CB / BN, M_ROWS / BM);
    vq_gemm<<<g, 256, 0, stream>>>(Ah, Al, Bh, Bl, cbsq, pVal, pPack);
    vq_reduce<<<M_ROWS / 4, 256, 0, stream>>>(pVal, pPack, fIdx, fCnt, fRows);
    vq_rescue<<<128, 1024, 0, stream>>>(z, cb, fCnt, fRows, fIdx);
    vq_gather<<<M_ROWS / 2, 256, 0, stream>>>((const float4*)cb, fIdx, (float4*)d_out,
                                              (float4*)d_out + (size_t)M_ROWS * CDIM / 4,
                                              (float*)d_out + 2 * (size_t)M_ROWS * CDIM);
}

// Round 2
// 1400.474 us; speedup vs baseline: 1.0061x; 1.0061x over previous
//
#include <hip/hip_runtime.h>
#include <hip/hip_fp16.h>

typedef _Float16 f16x8 __attribute__((ext_vector_type(8)));
typedef _Float16 f16x4 __attribute__((ext_vector_type(4)));
typedef float f32x4 __attribute__((ext_vector_type(4)));

static constexpr int M_ROWS = 32768;   // B*N
static constexpr int N_CB   = 8192;    // K codebook entries
static constexpr int CDIM   = 512;     // C
static constexpr int BM = 128, BN = 128, BKC = 32;
static constexpr int NBLK = N_CB / BN; // 64 column blocks
static constexpr float TAU = 0.02f;    // near-tie band; >> approx error (~1e-4)

// ---- workspace layout (bytes) ----
static constexpr size_t AH_OFF   = 0;
static constexpr size_t AL_OFF   = AH_OFF + (size_t)M_ROWS * CDIM * 2;
static constexpr size_t BH_OFF   = AL_OFF + (size_t)M_ROWS * CDIM * 2;
static constexpr size_t BL_OFF   = BH_OFF + (size_t)N_CB * CDIM * 2;
static constexpr size_t CBSQ_OFF = BL_OFF + (size_t)N_CB * CDIM * 2;
static constexpr size_t PVAL_OFF = CBSQ_OFF + (size_t)N_CB * 4;
static constexpr size_t PPACK_OFF= PVAL_OFF + (size_t)M_ROWS * NBLK * 4;
static constexpr size_t FIDX_OFF = PPACK_OFF + (size_t)M_ROWS * NBLK * 4;
static constexpr size_t FCNT_OFF = FIDX_OFF + (size_t)M_ROWS * 4;
static constexpr size_t FROWS_OFF= FCNT_OFF + 64;
// total ~96.3 MB

__device__ __forceinline__ void gload_lds16(const void* g, void* l) {
    __builtin_amdgcn_global_load_lds(
        (const __attribute__((address_space(1))) void*)g,
        (__attribute__((address_space(3))) void*)l, 16, 0, 0);
}

// fp32 -> (fp16 hi, fp16 lo) split, vectorized float4
__global__ void vq_split(const float4* __restrict__ in, _Float16* __restrict__ hi,
                         _Float16* __restrict__ lo, int n4) {
    int i = blockIdx.x * 256 + threadIdx.x;
    const int stride = gridDim.x * 256;
    for (; i < n4; i += stride) {
        float4 v = in[i];
        f16x4 h, l;
        h[0] = (_Float16)v.x; l[0] = (_Float16)(v.x - (float)h[0]);
        h[1] = (_Float16)v.y; l[1] = (_Float16)(v.y - (float)h[1]);
        h[2] = (_Float16)v.z; l[2] = (_Float16)(v.z - (float)h[2]);
        h[3] = (_Float16)v.w; l[3] = (_Float16)(v.w - (float)h[3]);
        *(f16x4*)(hi + (size_t)i * 4) = h;
        *(f16x4*)(lo + (size_t)i * 4) = l;
    }
}

// ||c_k||^2, one wave per codebook row (tree-sum: low rounding error)
__global__ void vq_cbsq(const float* __restrict__ cb, float* __restrict__ cbsq) {
    const int gw = (blockIdx.x * 256 + threadIdx.x) >> 6;
    const int lane = threadIdx.x & 63;
    if (gw >= N_CB) return;
    const float4* r = (const float4*)(cb + (size_t)gw * CDIM);
    float4 a = r[lane * 2], b = r[lane * 2 + 1];
    float s = a.x*a.x + a.y*a.y + a.z*a.z + a.w*a.w
            + b.x*b.x + b.y*b.y + b.z*b.z + b.w*b.w;
#pragma unroll
    for (int m = 1; m < 64; m <<= 1) s += __shfl_xor(s, m, 64);
    if (lane == 0) cbsq[gw] = s;
}

// Main pass: scores[m,n] = 2*dot(x_m, c_n) + cbsq[n] via fp16x2 3-MFMA GEMM,
// per-row min/idx/count(<= min+TAU) over each 128-col tile.
//
// LDS swizzle (rule 21, both-sides involution): physical (row, kc) holds
// global (row, kc ^ swz(row)), swz(row) = ((row>>1)&3)<<3 half-elements.
// Achieved with LINEAR global_load_lds dest + inverse-swizzled global source;
// ds_read applies the same XOR. Spreads consecutive lanes across all 8
// bank-quads -> 2-way residual aliasing (free per m136).
__launch_bounds__(256)
__global__ void vq_gemm(const _Float16* __restrict__ Ah, const _Float16* __restrict__ Al,
                        const _Float16* __restrict__ Bh, const _Float16* __restrict__ Bl,
                        const float* __restrict__ cbsq,
                        float* __restrict__ pVal, int* __restrict__ pPack) {
    __shared__ _Float16 As_h[BM][BKC];
    __shared__ _Float16 As_l[BM][BKC];
    __shared__ _Float16 Bs_h[BN][BKC];
    __shared__ _Float16 Bs_l[BN][BKC];
    __shared__ float mV[BM][2];
    __shared__ int   mI[BM][2];
    __shared__ int   mC[BM][2];

    const int tid = threadIdx.x;
    const int wave = tid >> 6, lane = tid & 63;
    const int mblk = blockIdx.y, nblk = blockIdx.x;
    const int wm = (wave >> 1) * 64, wn = (wave & 1) * 64;

    // stage-side source swizzle: lane l covers (row = base + (l>>2), kc = (l&3)*8);
    // swz(row) reduces to ((l>>3)&3)<<3 (row-base is a multiple of 16).
    const int ksw = ((lane & 3) * 8) ^ (((lane >> 3) & 3) << 3);
    // read-side: row = w? + (lane&15); swz(row) = (((lane&15)>>1)&3)<<3.
    const int kswr = (((lane & 15) >> 1) & 3) << 3;

    f32x4 acc[4][4] = {};

    for (int s = 0; s < CDIM / BKC; ++s) {
        __syncthreads();
        {
            const size_t gco = (size_t)(s * BKC) + ksw; // halves
#pragma unroll
            for (int it = 0; it < 2; ++it) {
                const int rl = wave * 16 + it * 64 + (lane >> 2);
                const int lofs = (wave * 16 + it * 64) * BKC; // halves, wave-uniform
                gload_lds16(Ah + (size_t)(mblk * BM + rl) * CDIM + gco, &As_h[0][0] + lofs);
                gload_lds16(Al + (size_t)(mblk * BM + rl) * CDIM + gco, &As_l[0][0] + lofs);
                gload_lds16(Bh + (size_t)(nblk * BN + rl) * CDIM + gco, &Bs_h[0][0] + lofs);
                gload_lds16(Bl + (size_t)(nblk * BN + rl) * CDIM + gco, &Bs_l[0][0] + lofs);
            }
        }
        asm volatile("s_waitcnt vmcnt(0)" ::: "memory");
        __syncthreads();

        const int k0 = (lane >> 4) * 8;
        const int kS = k0 ^ kswr;            // swizzled read column
        const int ar = wm + (lane & 15);
        f16x8 ah[4], al4[4];
#pragma unroll
        for (int mi = 0; mi < 4; ++mi) {
            ah[mi]  = *(const f16x8*)&As_h[ar + mi * 16][kS];
            al4[mi] = *(const f16x8*)&As_l[ar + mi * 16][kS];
        }
#pragma unroll
        for (int ni = 0; ni < 4; ++ni) {
            const int br = wn + ni * 16 + (lane & 15);
            f16x8 bh = *(const f16x8*)&Bs_h[br][kS];
            f16x8 bl = *(const f16x8*)&Bs_l[br][kS];
#pragma unroll
            for (int mi = 0; mi < 4; ++mi) {
                acc[mi][ni] = __builtin_amdgcn_mfma_f32_16x16x32_f16(ah[mi],  bh, acc[mi][ni], 0, 0, 0);
                acc[mi][ni] = __builtin_amdgcn_mfma_f32_16x16x32_f16(ah[mi],  bl, acc[mi][ni], 0, 0, 0);
                acc[mi][ni] = __builtin_amdgcn_mfma_f32_16x16x32_f16(al4[mi], bh, acc[mi][ni], 0, 0, 0);
            }
        }
    }
    __syncthreads();

    // ---- epilogue: per-row (min, idx, count within TAU) over this 128-col tile ----
    float cb4[4]; int col4[4];
#pragma unroll
    for (int ni = 0; ni < 4; ++ni) {
        const int c = nblk * BN + wn + ni * 16 + (lane & 15);
        col4[ni] = c; cb4[ni] = cbsq[c];
    }
#pragma unroll
    for (int mi = 0; mi < 4; ++mi) {
#pragma unroll
        for (int j = 0; j < 4; ++j) {
            float sv[4];
#pragma unroll
            for (int ni = 0; ni < 4; ++ni) sv[ni] = 2.0f * acc[mi][ni][j] + cb4[ni];
            float bv = sv[0]; int bi = col4[0];
#pragma unroll
            for (int ni = 1; ni < 4; ++ni)
                if (sv[ni] < bv) { bv = sv[ni]; bi = col4[ni]; } // cols increase with ni: tie keeps lower
#pragma unroll
            for (int m = 1; m < 16; m <<= 1) {
                float ov = __shfl_xor(bv, m, 64);
                int   oi = __shfl_xor(bi, m, 64);
                if (ov < bv || (ov == bv && oi < bi)) { bv = ov; bi = oi; }
            }
            int cnt = 0;
#pragma unroll
            for (int ni = 0; ni < 4; ++ni) cnt += (sv[ni] <= bv + TAU) ? 1 : 0;
#pragma unroll
            for (int m = 1; m < 16; m <<= 1) cnt += __shfl_xor(cnt, m, 64);
            if ((lane & 15) == 0) {
                const int r = wm + mi * 16 + (lane >> 4) * 4 + j;
                const int h = wn >> 6;
                mV[r][h] = bv; mI[r][h] = bi; mC[r][h] = cnt;
            }
        }
    }
    __syncthreads();
    if (tid < BM) {
        const float v0 = mV[tid][0], v1 = mV[tid][1];
        const int i0 = mI[tid][0], i1 = mI[tid][1];
        const int c0 = mC[tid][0], c1 = mC[tid][1];
        float bv; int bi;
        if (v1 < v0) { bv = v1; bi = i1; } else { bv = v0; bi = i0; } // tie -> lower idx (i0)
        int cnt = ((v0 <= bv + TAU) ? c0 : 0) + ((v1 <= bv + TAU) ? c1 : 0);
        if (cnt > 7) cnt = 7;
        const size_t o = (size_t)nblk * M_ROWS + (size_t)mblk * BM + tid; // transposed: coalesced store
        pVal[o] = bv;
        pPack[o] = (bi << 3) | cnt;
    }
}

// Merge 64 column-block partials per row; flag rows with >=2 candidates within TAU of global min.
// One thread per row; lane-contiguous (coalesced) loads across rows, loop over blocks.
__global__ void vq_reduce(const float* __restrict__ pVal, const int* __restrict__ pPack,
                          int* __restrict__ finalIdx, int* __restrict__ flagCnt,
                          int* __restrict__ flagRows) {
    const int row = blockIdx.x * 256 + threadIdx.x;
    float bv = 1e30f; int bblk = 0;
#pragma unroll 8
    for (int b = 0; b < NBLK; ++b) {
        const float v = pVal[(size_t)b * M_ROWS + row];
        if (v < bv) { bv = v; bblk = b; }   // strict <: first (lowest) block wins ties
    }
    int cnt = 0;
#pragma unroll 8
    for (int b = 0; b < NBLK; ++b) {
        const float v = pVal[(size_t)b * M_ROWS + row];
        if (v <= bv + TAU) cnt += pPack[(size_t)b * M_ROWS + row] & 7;
    }
    finalIdx[row] = pPack[(size_t)bblk * M_ROWS + row] >> 3;
    if (cnt >= 2) { int p = atomicAdd(flagCnt, 1); flagRows[p] = row; }
}

// Exact fp64 rescore of flagged rows (score = sum c*(c+2x); in_sq const -> dropped).
// One wave per candidate: coalesced float4 reads, butterfly-sum.
__launch_bounds__(1024)
__global__ void vq_rescue(const float* __restrict__ z, const float* __restrict__ cb,
                          const int* __restrict__ flagCnt, const int* __restrict__ flagRows,
                          int* __restrict__ finalIdx) {
    __shared__ float xs[CDIM];
    __shared__ double sV[16];
    __shared__ int sI[16];
    const int tid = threadIdx.x;
    const int wv = tid >> 6, lane = tid & 63;
    const int nf = *flagCnt;
    for (int f = blockIdx.x; f < nf; f += gridDim.x) {
        const int row = flagRows[f];
        __syncthreads();
        if (tid < CDIM) xs[tid] = z[(size_t)row * CDIM + tid];
        __syncthreads();
        const float4 x0 = ((const float4*)xs)[lane * 2];
        const float4 x1 = ((const float4*)xs)[lane * 2 + 1];
        double bv = 1e300; int bi = 0;
        for (int k = wv; k < N_CB; k += 16) {
            const float4* cr = (const float4*)(cb + (size_t)k * CDIM) + lane * 2;
            const float4 c0 = cr[0], c1 = cr[1];
            double s = 0.0;
            s += (double)c0.x * ((double)c0.x + 2.0 * (double)x0.x);
            s += (double)c0.y * ((double)c0.y + 2.0 * (double)x0.y);
            s += (double)c0.z * ((double)c0.z + 2.0 * (double)x0.z);
            s += (double)c0.w * ((double)c0.w + 2.0 * (double)x0.w);
            s += (double)c1.x * ((double)c1.x + 2.0 * (double)x1.x);
            s += (double)c1.y * ((double)c1.y + 2.0 * (double)x1.y);
            s += (double)c1.z * ((double)c1.z + 2.0 * (double)x1.z);
            s += (double)c1.w * ((double)c1.w + 2.0 * (double)x1.w);
#pragma unroll
            for (int m = 1; m < 64; m <<= 1) s += __shfl_xor(s, m, 64);
            if (s < bv) { bv = s; bi = k; }
        }
        if (lane == 0) { sV[wv] = bv; sI[wv] = bi; }
        __syncthreads();
        if (tid == 0) {
            double b = sV[0]; int i = sI[0];
            for (int w = 1; w < 16; ++w)
                if (sV[w] < b || (sV[w] == b && sI[w] < i)) { b = sV[w]; i = sI[w]; }
            finalIdx[row] = i;
        }
    }
}

// Gather codes into both outputs + idx as float.
__global__ void vq_gather(const float4* __restrict__ cb4, const int* __restrict__ finalIdx,
                          float4* __restrict__ out0, float4* __restrict__ out1,
                          float* __restrict__ out2) {
    const int tid = threadIdx.x;
    const int row = blockIdx.x * 2 + (tid >> 7);
    const int c4 = tid & 127;
    const int id = finalIdx[row];
    const float4 v = cb4[(size_t)id * 128 + c4];
    const size_t o = (size_t)row * 128 + c4;
    out0[o] = v;
    out1[o] = v;
    if (c4 == 0) out2[row] = (float)id;
}

extern "C" void kernel_launch(void* const* d_in, const int* in_sizes, int n_in,
                              void* d_out, int out_size, void* d_ws, size_t ws_size,
                              hipStream_t stream) {
    const float* z  = (const float*)d_in[0];
    const float* cb = (const float*)d_in[1];
    char* ws = (char*)d_ws;
    _Float16* Ah = (_Float16*)(ws + AH_OFF);
    _Float16* Al = (_Float16*)(ws + AL_OFF);
    _Float16* Bh = (_Float16*)(ws + BH_OFF);
    _Float16* Bl = (_Float16*)(ws + BL_OFF);
    float* cbsq  = (float*)(ws + CBSQ_OFF);
    float* pVal  = (float*)(ws + PVAL_OFF);
    int* pPack   = (int*)(ws + PPACK_OFF);
    int* fIdx    = (int*)(ws + FIDX_OFF);
    int* fCnt    = (int*)(ws + FCNT_OFF);
    int* fRows   = (int*)(ws + FROWS_OFF);

    hipMemsetAsync(fCnt, 0, 4, stream);
    vq_split<<<2048, 256, 0, stream>>>((const float4*)z, Ah, Al, M_ROWS * CDIM / 4);
    vq_split<<<1024, 256, 0, stream>>>((const float4*)cb, Bh, Bl, N_CB * CDIM / 4);
    vq_cbsq<<<N_CB / 4, 256, 0, stream>>>(cb, cbsq);
    dim3 g(N_CB / BN, M_ROWS / BM);
    vq_gemm<<<g, 256, 0, stream>>>(Ah, Al, Bh, Bl, cbsq, pVal, pPack);
    vq_reduce<<<M_ROWS / 256, 256, 0, stream>>>(pVal, pPack, fIdx, fCnt, fRows);
    vq_rescue<<<128, 1024, 0, stream>>>(z, cb, fCnt, fRows, fIdx);
    vq_gather<<<M_ROWS / 2, 256, 0, stream>>>((const float4*)cb, fIdx, (float4*)d_out,
                                              (float4*)d_out + (size_t)M_ROWS * CDIM / 4,
                                              (float*)d_out + 2 * (size_t)M_ROWS * CDIM);
}

// Round 3
// 1207.043 us; speedup vs baseline: 1.1673x; 1.1603x over previous
//
#include <hip/hip_runtime.h>
#include <hip/hip_fp16.h>

typedef _Float16 f16x8 __attribute__((ext_vector_type(8)));
typedef _Float16 f16x4 __attribute__((ext_vector_type(4)));
typedef float f32x4 __attribute__((ext_vector_type(4)));

static constexpr int M_ROWS = 32768;   // B*N
static constexpr int N_CB   = 8192;    // K codebook entries
static constexpr int CDIM   = 512;     // C
static constexpr int BM = 256, BN = 128, BKC = 32;   // block tile; 4 waves of 128x64
static constexpr int NBLK = N_CB / BN; // 64 column blocks
static constexpr float TAU = 0.01f;    // near-tie band; score err ~1e-3 -> 5x margin

// ---- workspace layout (bytes) ----
static constexpr size_t AH_OFF   = 0;
static constexpr size_t AL_OFF   = AH_OFF + (size_t)M_ROWS * CDIM * 2;
static constexpr size_t BH_OFF   = AL_OFF + (size_t)M_ROWS * CDIM * 2;
static constexpr size_t BL_OFF   = BH_OFF + (size_t)N_CB * CDIM * 2;
static constexpr size_t CBSQ_OFF = BL_OFF + (size_t)N_CB * 2;
static constexpr size_t CBSQ_OFF2= BL_OFF + (size_t)N_CB * CDIM * 2;
static constexpr size_t PVAL_OFF = CBSQ_OFF2 + (size_t)N_CB * 4;
static constexpr size_t PPACK_OFF= PVAL_OFF + (size_t)M_ROWS * NBLK * 4;
static constexpr size_t FIDX_OFF = PPACK_OFF + (size_t)M_ROWS * NBLK * 4;
static constexpr size_t FCNT_OFF = FIDX_OFF + (size_t)M_ROWS * 4;
static constexpr size_t FROWS_OFF= FCNT_OFF + 64;
// total ~96.4 MB

__device__ __forceinline__ void gload_lds16(const void* g, void* l) {
    __builtin_amdgcn_global_load_lds(
        (const __attribute__((address_space(1))) void*)g,
        (__attribute__((address_space(3))) void*)l, 16, 0, 0);
}

// fp32 -> (fp16 hi, fp16 lo) split, vectorized float4
__global__ void vq_split(const float4* __restrict__ in, _Float16* __restrict__ hi,
                         _Float16* __restrict__ lo, int n4) {
    int i = blockIdx.x * 256 + threadIdx.x;
    const int stride = gridDim.x * 256;
    for (; i < n4; i += stride) {
        float4 v = in[i];
        f16x4 h, l;
        h[0] = (_Float16)v.x; l[0] = (_Float16)(v.x - (float)h[0]);
        h[1] = (_Float16)v.y; l[1] = (_Float16)(v.y - (float)h[1]);
        h[2] = (_Float16)v.z; l[2] = (_Float16)(v.z - (float)h[2]);
        h[3] = (_Float16)v.w; l[3] = (_Float16)(v.w - (float)h[3]);
        *(f16x4*)(hi + (size_t)i * 4) = h;
        *(f16x4*)(lo + (size_t)i * 4) = l;
    }
}

// ||c_k||^2, one wave per codebook row (tree-sum: low rounding error)
__global__ void vq_cbsq(const float* __restrict__ cb, float* __restrict__ cbsq) {
    const int gw = (blockIdx.x * 256 + threadIdx.x) >> 6;
    const int lane = threadIdx.x & 63;
    if (gw >= N_CB) return;
    const float4* r = (const float4*)(cb + (size_t)gw * CDIM);
    float4 a = r[lane * 2], b = r[lane * 2 + 1];
    float s = a.x*a.x + a.y*a.y + a.z*a.z + a.w*a.w
            + b.x*b.x + b.y*b.y + b.z*b.z + b.w*b.w;
#pragma unroll
    for (int m = 1; m < 64; m <<= 1) s += __shfl_xor(s, m, 64);
    if (lane == 0) cbsq[gw] = s;
}

// Main pass: scores[m,n] = 2*dot(x_m, c_n) + cbsq[n] via fp16x2 3-MFMA GEMM.
// Block 256x128, 4 waves each owning 128x64 (8x4 fragments) -> LDS read
// bytes/FLOP -27% vs 64x64 wave tile, 96 MFMA per barrier-pair per wave.
// LDS swizzle (rule 21 both-sides involution) carried from round 2:
// physical (row,kc) holds global kc ^ ((row>>1)&3)<<3; linear gload_lds dest +
// inverse-swizzled global source + swizzled ds_read.
__launch_bounds__(256, 2)
__global__ void vq_gemm(const _Float16* __restrict__ Ah, const _Float16* __restrict__ Al,
                        const _Float16* __restrict__ Bh, const _Float16* __restrict__ Bl,
                        const float* __restrict__ cbsq,
                        float* __restrict__ pVal, int* __restrict__ pPack) {
    __shared__ _Float16 As_h[BM][BKC];
    __shared__ _Float16 As_l[BM][BKC];
    __shared__ _Float16 Bs_h[BN][BKC];
    __shared__ _Float16 Bs_l[BN][BKC];
    __shared__ float mV[BM][2];
    __shared__ int   mI[BM][2];
    __shared__ int   mC[BM][2];

    const int tid = threadIdx.x;
    const int wave = tid >> 6, lane = tid & 63;
    const int mblk = blockIdx.y, nblk = blockIdx.x;
    const int wm = (wave >> 1) * 128, wn = (wave & 1) * 64;

    // stage-side source swizzle (row-base multiple of 16): ((l>>3)&3)<<3
    const int ksw = ((lane & 3) * 8) ^ (((lane >> 3) & 3) << 3);
    // read-side: swz(row) with row = 16-aligned + (lane&15)
    const int kswr = (((lane & 15) >> 1) & 3) << 3;

    f32x4 acc[8][4] = {};

    for (int s = 0; s < CDIM / BKC; ++s) {
        __syncthreads();
        {
            const size_t gco = (size_t)(s * BKC) + ksw; // halves
#pragma unroll
            for (int it = 0; it < 4; ++it) {           // A: 256 rows, 16/chunk
                const int rl = wave * 16 + it * 64 + (lane >> 2);
                const int lofs = (wave * 16 + it * 64) * BKC;
                gload_lds16(Ah + (size_t)(mblk * BM + rl) * CDIM + gco, &As_h[0][0] + lofs);
                gload_lds16(Al + (size_t)(mblk * BM + rl) * CDIM + gco, &As_l[0][0] + lofs);
            }
#pragma unroll
            for (int it = 0; it < 2; ++it) {           // B: 128 rows
                const int rl = wave * 16 + it * 64 + (lane >> 2);
                const int lofs = (wave * 16 + it * 64) * BKC;
                gload_lds16(Bh + (size_t)(nblk * BN + rl) * CDIM + gco, &Bs_h[0][0] + lofs);
                gload_lds16(Bl + (size_t)(nblk * BN + rl) * CDIM + gco, &Bs_l[0][0] + lofs);
            }
        }
        asm volatile("s_waitcnt vmcnt(0)" ::: "memory");
        __syncthreads();

        const int k0 = (lane >> 4) * 8;
        const int kS = k0 ^ kswr;            // swizzled read column
        // B fragments register-cached across all 8 mi (32 VGPR)
        f16x8 bh[4], bl[4];
#pragma unroll
        for (int ni = 0; ni < 4; ++ni) {
            const int br = wn + ni * 16 + (lane & 15);
            bh[ni] = *(const f16x8*)&Bs_h[br][kS];
            bl[ni] = *(const f16x8*)&Bs_l[br][kS];
        }
#pragma unroll
        for (int mi = 0; mi < 8; ++mi) {
            const int ar = wm + mi * 16 + (lane & 15);
            f16x8 ah = *(const f16x8*)&As_h[ar][kS];
            f16x8 al = *(const f16x8*)&As_l[ar][kS];
#pragma unroll
            for (int ni = 0; ni < 4; ++ni) {
                acc[mi][ni] = __builtin_amdgcn_mfma_f32_16x16x32_f16(ah, bh[ni], acc[mi][ni], 0, 0, 0);
                acc[mi][ni] = __builtin_amdgcn_mfma_f32_16x16x32_f16(ah, bl[ni], acc[mi][ni], 0, 0, 0);
                acc[mi][ni] = __builtin_amdgcn_mfma_f32_16x16x32_f16(al, bh[ni], acc[mi][ni], 0, 0, 0);
            }
        }
    }
    __syncthreads();

    // ---- epilogue: per-row (min, idx, count within TAU) over this 128-col tile ----
    float cb4[4]; int col4[4];
#pragma unroll
    for (int ni = 0; ni < 4; ++ni) {
        const int c = nblk * BN + wn + ni * 16 + (lane & 15);
        col4[ni] = c; cb4[ni] = cbsq[c];
    }
#pragma unroll
    for (int mi = 0; mi < 8; ++mi) {
#pragma unroll
        for (int j = 0; j < 4; ++j) {
            float sv[4];
#pragma unroll
            for (int ni = 0; ni < 4; ++ni) sv[ni] = 2.0f * acc[mi][ni][j] + cb4[ni];
            float bv = sv[0]; int bi = col4[0];
#pragma unroll
            for (int ni = 1; ni < 4; ++ni)
                if (sv[ni] < bv) { bv = sv[ni]; bi = col4[ni]; } // tie keeps lower col
#pragma unroll
            for (int m = 1; m < 16; m <<= 1) {
                float ov = __shfl_xor(bv, m, 64);
                int   oi = __shfl_xor(bi, m, 64);
                if (ov < bv || (ov == bv && oi < bi)) { bv = ov; bi = oi; }
            }
            int cnt = 0;
#pragma unroll
            for (int ni = 0; ni < 4; ++ni) cnt += (sv[ni] <= bv + TAU) ? 1 : 0;
#pragma unroll
            for (int m = 1; m < 16; m <<= 1) cnt += __shfl_xor(cnt, m, 64);
            if ((lane & 15) == 0) {
                const int r = wm + mi * 16 + (lane >> 4) * 4 + j;
                const int h = wn >> 6;
                mV[r][h] = bv; mI[r][h] = bi; mC[r][h] = cnt;
            }
        }
    }
    __syncthreads();
    if (tid < BM) {
        const float v0 = mV[tid][0], v1 = mV[tid][1];
        const int i0 = mI[tid][0], i1 = mI[tid][1];
        const int c0 = mC[tid][0], c1 = mC[tid][1];
        float bv; int bi;
        if (v1 < v0) { bv = v1; bi = i1; } else { bv = v0; bi = i0; } // tie -> lower idx (i0)
        int cnt = ((v0 <= bv + TAU) ? c0 : 0) + ((v1 <= bv + TAU) ? c1 : 0);
        if (cnt > 7) cnt = 7;
        const size_t o = (size_t)nblk * M_ROWS + (size_t)mblk * BM + tid; // coalesced store
        pVal[o] = bv;
        pPack[o] = (bi << 3) | cnt;
    }
}

// Merge 64 column-block partials per row; flag rows with >=2 candidates within TAU of global min.
__global__ void vq_reduce(const float* __restrict__ pVal, const int* __restrict__ pPack,
                          int* __restrict__ finalIdx, int* __restrict__ flagCnt,
                          int* __restrict__ flagRows) {
    const int row = blockIdx.x * 256 + threadIdx.x;
    float bv = 1e30f; int bblk = 0;
#pragma unroll 8
    for (int b = 0; b < NBLK; ++b) {
        const float v = pVal[(size_t)b * M_ROWS + row];
        if (v < bv) { bv = v; bblk = b; }   // strict <: first (lowest) block wins ties
    }
    int cnt = 0;
#pragma unroll 8
    for (int b = 0; b < NBLK; ++b) {
        const float v = pVal[(size_t)b * M_ROWS + row];
        if (v <= bv + TAU) cnt += pPack[(size_t)b * M_ROWS + row] & 7;
    }
    finalIdx[row] = pPack[(size_t)bblk * M_ROWS + row] >> 3;
    if (cnt >= 2) { int p = atomicAdd(flagCnt, 1); flagRows[p] = row; }
}

// Exact fp64 rescore of flagged rows, RESTRICTED to candidate blocks
// (block-min <= global-min + TAU): ~64x less work than a full rescan.
// One wave per flagged row; each lane owns 2 entries of a candidate block.
__launch_bounds__(256)
__global__ void vq_rescue(const float* __restrict__ z, const float* __restrict__ cb,
                          const float* __restrict__ pVal,
                          const int* __restrict__ flagCnt, const int* __restrict__ flagRows,
                          int* __restrict__ finalIdx) {
    __shared__ float xs[4][CDIM];
    const int tid = threadIdx.x;
    const int wv = tid >> 6, lane = tid & 63;
    const int nf = *flagCnt;
    for (int f = blockIdx.x * 4 + wv; f < nf; f += gridDim.x * 4) {
        const int row = flagRows[f];
        // stage x row into this wave's LDS slice (wave-private, no barrier)
        ((float4*)xs[wv])[lane * 2]     = ((const float4*)(z + (size_t)row * CDIM))[lane * 2];
        ((float4*)xs[wv])[lane * 2 + 1] = ((const float4*)(z + (size_t)row * CDIM))[lane * 2 + 1];
        // lane b holds block b's min
        const float pv = pVal[(size_t)lane * M_ROWS + row];
        float gm = pv;
#pragma unroll
        for (int m = 1; m < 64; m <<= 1) gm = fminf(gm, __shfl_xor(gm, m, 64));
        unsigned long long mask = __ballot(pv <= gm + TAU);
        asm volatile("s_waitcnt lgkmcnt(0)" ::: "memory");
        double bv = 1e300; int bi = 0x7fffffff;
        while (mask) {
            const int b = __ffsll((long long)mask) - 1;
            mask &= mask - 1;
#pragma unroll
            for (int e = 0; e < 2; ++e) {
                const int k = b * BN + e * 64 + lane;
                const float4* cr = (const float4*)(cb + (size_t)k * CDIM);
                double s = 0.0;
                for (int j = 0; j < CDIM / 4; ++j) {
                    const float4 c4 = cr[j];
                    const float4 x4 = ((const float4*)xs[wv])[j]; // broadcast
                    s += (double)c4.x * ((double)c4.x + 2.0 * (double)x4.x);
                    s += (double)c4.y * ((double)c4.y + 2.0 * (double)x4.y);
                    s += (double)c4.z * ((double)c4.z + 2.0 * (double)x4.z);
                    s += (double)c4.w * ((double)c4.w + 2.0 * (double)x4.w);
                }
                if (s < bv || (s == bv && k < bi)) { bv = s; bi = k; }
            }
        }
#pragma unroll
        for (int m = 1; m < 64; m <<= 1) {
            const double ov = __shfl_xor(bv, m, 64);
            const int   oi = __shfl_xor(bi, m, 64);
            if (ov < bv || (ov == bv && oi < bi)) { bv = ov; bi = oi; }
        }
        if (lane == 0) finalIdx[row] = bi;
    }
}

// Gather codes into both outputs + idx as float.
__global__ void vq_gather(const float4* __restrict__ cb4, const int* __restrict__ finalIdx,
                          float4* __restrict__ out0, float4* __restrict__ out1,
                          float* __restrict__ out2) {
    const int tid = threadIdx.x;
    const int row = blockIdx.x * 2 + (tid >> 7);
    const int c4 = tid & 127;
    const int id = finalIdx[row];
    const float4 v = cb4[(size_t)id * 128 + c4];
    const size_t o = (size_t)row * 128 + c4;
    out0[o] = v;
    out1[o] = v;
    if (c4 == 0) out2[row] = (float)id;
}

extern "C" void kernel_launch(void* const* d_in, const int* in_sizes, int n_in,
                              void* d_out, int out_size, void* d_ws, size_t ws_size,
                              hipStream_t stream) {
    const float* z  = (const float*)d_in[0];
    const float* cb = (const float*)d_in[1];
    char* ws = (char*)d_ws;
    _Float16* Ah = (_Float16*)(ws + AH_OFF);
    _Float16* Al = (_Float16*)(ws + AL_OFF);
    _Float16* Bh = (_Float16*)(ws + BH_OFF);
    _Float16* Bl = (_Float16*)(ws + BL_OFF);
    float* cbsq  = (float*)(ws + CBSQ_OFF2);
    float* pVal  = (float*)(ws + PVAL_OFF);
    int* pPack   = (int*)(ws + PPACK_OFF);
    int* fIdx    = (int*)(ws + FIDX_OFF);
    int* fCnt    = (int*)(ws + FCNT_OFF);
    int* fRows   = (int*)(ws + FROWS_OFF);

    hipMemsetAsync(fCnt, 0, 4, stream);
    vq_split<<<2048, 256, 0, stream>>>((const float4*)z, Ah, Al, M_ROWS * CDIM / 4);
    vq_split<<<1024, 256, 0, stream>>>((const float4*)cb, Bh, Bl, N_CB * CDIM / 4);
    vq_cbsq<<<N_CB / 4, 256, 0, stream>>>(cb, cbsq);
    dim3 g(N_CB / BN, M_ROWS / BM);
    vq_gemm<<<g, 256, 0, stream>>>(Ah, Al, Bh, Bl, cbsq, pVal, pPack);
    vq_reduce<<<M_ROWS / 256, 256, 0, stream>>>(pVal, pPack, fIdx, fCnt, fRows);
    vq_rescue<<<256, 256, 0, stream>>>(z, cb, pVal, fCnt, fRows, fIdx);
    vq_gather<<<M_ROWS / 2, 256, 0, stream>>>((const float4*)cb, fIdx, (float4*)d_out,
                                              (float4*)d_out + (size_t)M_ROWS * CDIM / 4,
                                              (float*)d_out + 2 * (size_t)M_ROWS * CDIM);
}